// Round 6
// baseline (483.411 us; speedup 1.0000x reference)
//
#include <hip/hip_runtime.h>
#include <hip/hip_bf16.h>

typedef __attribute__((ext_vector_type(8))) short short8;
typedef __attribute__((ext_vector_type(4))) float f32x4;

#define S_LEN 2048
#define NH 16
#define NKV 8
#define HD 64
#define WIN 512
#define DMODEL 1024
#define LOG2_10000 13.287712379549449f

// async 16B global -> LDS (wave-uniform LDS base + lane*16 semantics)
#define GLOAD16(g, l)                                                        \
    __builtin_amdgcn_global_load_lds(                                        \
        (const __attribute__((address_space(1))) unsigned int*)(g),          \
        (__attribute__((address_space(3))) unsigned int*)(l), 16, 0, 0)

// ---------------- cast X (fp32 -> bf16), vectorized ----------------
__global__ void cast_bf16_kernel(const float* __restrict__ X,
                                 __hip_bfloat16* __restrict__ Y, int n) {
    int i = (blockIdx.x * 256 + threadIdx.x) * 4;
    if (i + 3 < n) {
        float4 v = *reinterpret_cast<const float4*>(X + i);
        Y[i + 0] = __float2bfloat16(v.x);
        Y[i + 1] = __float2bfloat16(v.y);
        Y[i + 2] = __float2bfloat16(v.z);
        Y[i + 3] = __float2bfloat16(v.w);
    }
}

// ------- fused transpose+cast of all 4 weights (z selects matrix) -------
__global__ void transpose_cast4_kernel(const float* __restrict__ W0,
                                       const float* __restrict__ W1,
                                       const float* __restrict__ W2,
                                       const float* __restrict__ W3,
                                       __hip_bfloat16* __restrict__ WqkvT,
                                       __hip_bfloat16* __restrict__ WoT) {
    __shared__ float tile[32][33];
    const int K = DMODEL;
    const float* W;
    __hip_bfloat16* WT;
    int N;
    switch (blockIdx.z) {
        case 0: W = W0; WT = WqkvT;                          N = 1024; break;
        case 1: W = W1; WT = WqkvT + (size_t)1024 * K;       N = 512;  break;
        case 2: W = W2; WT = WqkvT + (size_t)1536 * K;       N = 512;  break;
        default: W = W3; WT = WoT;                           N = 1024; break;
    }
    if ((int)blockIdx.x * 32 >= N) return;
    int nx = blockIdx.x * 32 + threadIdx.x;
    int k0 = blockIdx.y * 32;
#pragma unroll
    for (int r = 0; r < 4; ++r) {
        int k = k0 + threadIdx.y + r * 8;
        tile[threadIdx.y + r * 8][threadIdx.x] = W[(size_t)k * N + nx];
    }
    __syncthreads();
#pragma unroll
    for (int r = 0; r < 4; ++r) {
        int nn = blockIdx.x * 32 + threadIdx.y + r * 8;
        int kk = k0 + threadIdx.x;
        WT[(size_t)nn * K + kk] = __float2bfloat16(tile[threadIdx.x][threadIdx.y + r * 8]);
    }
}

// ---------------- m97-style GEMM: 64(M)x128(N) tile, 128 thr = 2 waves ----------
// MODE 0: fused QKV epilogue with in-register RoPE on Q/K regions
//         (pairs (d, d+32) are acc[mi][ni] / acc[mi][ni+2]); V -> transposed.
// MODE 1: fp32 C (row stride N).
template <int MODE>
__global__ __launch_bounds__(128) void gemm128_kernel(
    const __hip_bfloat16* __restrict__ A,
    const __hip_bfloat16* __restrict__ BT,
    void* __restrict__ o0, void* __restrict__ o1, void* __restrict__ o2,
    int N, int K) {
    __shared__ __hip_bfloat16 ldsA[64 * 32];    // 4 KB
    __shared__ __hip_bfloat16 ldsB[128 * 32];   // 8 KB
    const int tx = threadIdx.x;
    const int wave = tx >> 6;
    const int lane = tx & 63;
    const int l16 = lane & 15;
    const int quad = lane >> 4;
    const int col0 = blockIdx.x * 128;
    const int row0 = blockIdx.y * 64;
    const int wcol = wave * 64;

    f32x4 acc[4][4] = {};

    const int arow = tx >> 2;
    const int kc8 = (tx & 3) * 8;
    const __hip_bfloat16* gA = A + (size_t)(row0 + arow) * K + kc8;
    const __hip_bfloat16* gB = BT + (size_t)(col0 + arow) * K + kc8;
    char* lA = (char*)ldsA + tx * 16;
    char* lB = (char*)ldsB + tx * 16;

    for (int k0 = 0; k0 < K; k0 += 32) {
        GLOAD16(gA + k0, lA);
        GLOAD16(gA + (size_t)32 * K + k0, lA + 2048);
#pragma unroll
        for (int r = 0; r < 4; ++r)
            GLOAD16(gB + (size_t)r * 32 * K + k0, lB + r * 2048);
        __syncthreads();
        short8 af[4], bf[4];
#pragma unroll
        for (int i = 0; i < 4; ++i) {
            af[i] = *reinterpret_cast<const short8*>(ldsA + (i * 16 + l16) * 32 + quad * 8);
            bf[i] = *reinterpret_cast<const short8*>(ldsB + (wcol + i * 16 + l16) * 32 + quad * 8);
        }
#pragma unroll
        for (int mi = 0; mi < 4; ++mi)
#pragma unroll
            for (int ni = 0; ni < 4; ++ni)
                acc[mi][ni] = __builtin_amdgcn_mfma_f32_16x16x32_bf16(
                    af[mi], bf[ni], acc[mi][ni], 0, 0, 0);
        __syncthreads();
    }

    if (MODE == 0) {
        const bool isQ = (col0 < DMODEL);
        const bool isK = (col0 >= DMODEL) && (col0 < DMODEL + 512);
        if (isQ || isK) {
            // in-register RoPE: lane's d = ni*16 + l16 for ni<2, pair at ni+2
            float invf[2];
            invf[0] = exp2f(-(float)(l16)      * (LOG2_10000 / 32.0f));
            invf[1] = exp2f(-(float)(16 + l16) * (LOG2_10000 / 32.0f));
#pragma unroll
            for (int mi = 0; mi < 4; ++mi)
#pragma unroll
                for (int r = 0; r < 4; ++r) {
                    int srow = (row0 + mi * 16 + quad * 4 + r) & (S_LEN - 1);
#pragma unroll
                    for (int ni = 0; ni < 2; ++ni) {
                        float ang = (float)srow * invf[ni];
                        float c = cosf(ang), s = sinf(ang);
                        float x1 = acc[mi][ni][r], x2 = acc[mi][ni + 2][r];
                        acc[mi][ni][r]     = x1 * c - x2 * s;
                        acc[mi][ni + 2][r] = x2 * c + x1 * s;
                    }
                }
            __hip_bfloat16* Co = (__hip_bfloat16*)(isQ ? o0 : o1);
            int cbase = isQ ? col0 : col0 - DMODEL;
            int rowstride = isQ ? (NH * HD) : (NKV * HD);
#pragma unroll
            for (int mi = 0; mi < 4; ++mi)
#pragma unroll
                for (int ni = 0; ni < 4; ++ni) {
                    size_t col = cbase + wcol + ni * 16 + l16;
#pragma unroll
                    for (int r = 0; r < 4; ++r)
                        Co[(size_t)(row0 + mi * 16 + quad * 4 + r) * rowstride + col] =
                            __float2bfloat16(acc[mi][ni][r]);
                }
        } else {                                   // V region -> transposed VT
            __hip_bfloat16* VTo = (__hip_bfloat16*)o2;
            int bb = row0 >> 11;
#pragma unroll
            for (int mi = 0; mi < 4; ++mi) {
                int s = ((row0 + mi * 16 + quad * 4) & (S_LEN - 1));
#pragma unroll
                for (int ni = 0; ni < 4; ++ni) {
                    int colv = col0 - 1536 + wcol + ni * 16 + l16;   // 0..511
                    int vh = colv >> 6, d = colv & 63;
                    alignas(8) __hip_bfloat16 hv[4];
#pragma unroll
                    for (int r = 0; r < 4; ++r) hv[r] = __float2bfloat16(acc[mi][ni][r]);
                    *reinterpret_cast<ushort4*>(
                        VTo + ((size_t)(bb * NKV + vh) * HD + d) * S_LEN + s) =
                        *reinterpret_cast<ushort4*>(hv);
                }
            }
        }
    } else {                                       // fp32 C
        float* Co = (float*)o0;
#pragma unroll
        for (int mi = 0; mi < 4; ++mi)
#pragma unroll
            for (int ni = 0; ni < 4; ++ni) {
                size_t col = col0 + wcol + ni * 16 + l16;
#pragma unroll
                for (int r = 0; r < 4; ++r)
                    Co[(size_t)(row0 + mi * 16 + quad * 4 + r) * N + col] = acc[mi][ni][r];
            }
    }
}

// ---------------- MFMA flash attention (S^T, double-buffered staging) ----------
// grid (S/64, NH, B), 256 thr = 4 waves; lane owns 1 query (col) x 16 keys.
// Register-prefetch next K/V chunk during compute; ONE barrier per chunk.
// Softmax in exp2 domain (scale folds in log2e).
__global__ __launch_bounds__(256) void attn_mfma_kernel(
    const __hip_bfloat16* __restrict__ Q,
    const __hip_bfloat16* __restrict__ K,
    const __hip_bfloat16* __restrict__ VT,
    __hip_bfloat16* __restrict__ O) {
    __shared__ __hip_bfloat16 ldsK[2][64][80];
    __shared__ __hip_bfloat16 ldsVT[2][64][80];
    __shared__ __hip_bfloat16 ldsP[4][16][80];
    const int tx = threadIdx.x;
    const int wave = tx >> 6;
    const int lane = tx & 63;
    const int l16 = lane & 15;
    const int quad = lane >> 4;
    const int q0 = blockIdx.x * 64;
    const int h = blockIdx.y;
    const int b = blockIdx.z;
    const int kvh = h >> 1;
    const int qi = q0 + wave * 16 + l16;

    short8 aq0, aq1;
    {
        const __hip_bfloat16* qp =
            Q + (size_t)(b * S_LEN + qi) * (NH * HD) + h * HD + quad * 8;
        aq0 = *reinterpret_cast<const short8*>(qp);
        aq1 = *reinterpret_cast<const short8*>(qp + 32);
    }
    f32x4 acc_o[4] = {};
    float m = -1e30f, l = 0.f;
    const float SL2 = 0.125f * 1.4426950408889634f;   // scale * log2(e)

    const int s_a = tx >> 3;           // staging row   (0..31 per round)
    const int s_e = (tx & 7) * 8;      // staging elem offset
    uint4 kr[2], vr[2];
    auto load_chunk = [&](int j0) {
#pragma unroll
        for (int r = 0; r < 2; ++r) {
            int a = s_a + r * 32;
            kr[r] = *reinterpret_cast<const uint4*>(
                K + (size_t)(b * S_LEN + j0 + a) * (NKV * HD) + kvh * HD + s_e);
            vr[r] = *reinterpret_cast<const uint4*>(
                VT + ((size_t)(b * NKV + kvh) * HD + a) * S_LEN + j0 + s_e);
        }
    };
    const int kstart = (q0 >= WIN) ? (q0 - WIN) : 0;
    load_chunk(kstart);
    int buf = 0;

    for (int j0 = kstart; j0 <= q0; j0 += 64) {
        // store prefetched chunk (dbuf: other buffer's readers already past
        // the previous barrier), then prefetch next
#pragma unroll
        for (int r = 0; r < 2; ++r) {
            int a = s_a + r * 32;
            *reinterpret_cast<uint4*>(&ldsK[buf][a][s_e]) = kr[r];
            *reinterpret_cast<uint4*>(&ldsVT[buf][a][s_e]) = vr[r];
        }
        if (j0 + 64 <= q0) load_chunk(j0 + 64);
        __syncthreads();

        // S^T = K @ Q^T : rows = keys, cols = queries
        f32x4 sacc[4] = {};
#pragma unroll
        for (int t = 0; t < 4; ++t) {
            short8 bk0 = *reinterpret_cast<const short8*>(&ldsK[buf][t * 16 + l16][quad * 8]);
            short8 bk1 = *reinterpret_cast<const short8*>(&ldsK[buf][t * 16 + l16][32 + quad * 8]);
            sacc[t] = __builtin_amdgcn_mfma_f32_16x16x32_bf16(bk0, aq0, sacc[t], 0, 0, 0);
            sacc[t] = __builtin_amdgcn_mfma_f32_16x16x32_bf16(bk1, aq1, sacc[t], 0, 0, 0);
        }

        // scale into exp2 domain (+ mask only diagonal / trailing chunk)
        float sv[4][4];
        const bool need_mask = (j0 == q0) || (q0 >= WIN && j0 == kstart);
        if (need_mask) {
#pragma unroll
            for (int t = 0; t < 4; ++t)
#pragma unroll
                for (int r = 0; r < 4; ++r) {
                    int j = j0 + t * 16 + quad * 4 + r;
                    bool ok = (j <= qi) && (j + WIN >= qi);
                    sv[t][r] = ok ? sacc[t][r] * SL2 : -1e30f;
                }
        } else {
#pragma unroll
            for (int t = 0; t < 4; ++t)
#pragma unroll
                for (int r = 0; r < 4; ++r) sv[t][r] = sacc[t][r] * SL2;
        }

        // online softmax (exp2 domain): in-lane reduce + 2 shuffles
        float cm = -1e30f;
#pragma unroll
        for (int t = 0; t < 4; ++t)
#pragma unroll
            for (int r = 0; r < 4; ++r) cm = fmaxf(cm, sv[t][r]);
        cm = fmaxf(cm, __shfl_xor(cm, 16));
        cm = fmaxf(cm, __shfl_xor(cm, 32));
        float mn = fmaxf(m, cm);
        float alpha = exp2f(m - mn);
        m = mn;
        float sp = 0.f;
#pragma unroll
        for (int t = 0; t < 4; ++t)
#pragma unroll
            for (int r = 0; r < 4; ++r) { sv[t][r] = exp2f(sv[t][r] - mn); sp += sv[t][r]; }
        sp += __shfl_xor(sp, 16);
        sp += __shfl_xor(sp, 32);
        l = l * alpha + sp;
#pragma unroll
        for (int t = 0; t < 4; ++t)
#pragma unroll
            for (int r = 0; r < 4; ++r) acc_o[t][r] *= alpha;

        // P^T -> LDS (packed b64), then O^T += VT @ P^T (same-wave, in order)
#pragma unroll
        for (int t = 0; t < 4; ++t) {
            alignas(8) __hip_bfloat16 hp[4];
#pragma unroll
            for (int r = 0; r < 4; ++r) hp[r] = __float2bfloat16(sv[t][r]);
            *reinterpret_cast<ushort4*>(&ldsP[wave][l16][t * 16 + quad * 4]) =
                *reinterpret_cast<ushort4*>(hp);
        }
#pragma unroll
        for (int ks = 0; ks < 2; ++ks) {
            short8 pf = *reinterpret_cast<const short8*>(&ldsP[wave][l16][ks * 32 + quad * 8]);
#pragma unroll
            for (int t = 0; t < 4; ++t) {
                short8 vf = *reinterpret_cast<const short8*>(
                    &ldsVT[buf][t * 16 + l16][ks * 32 + quad * 8]);
                acc_o[t] = __builtin_amdgcn_mfma_f32_16x16x32_bf16(vf, pf, acc_o[t], 0, 0, 0);
            }
        }
        buf ^= 1;
    }

    float inv = 1.f / l;
    __hip_bfloat16* op = O + (size_t)(b * S_LEN + qi) * (NH * HD) + h * HD;
#pragma unroll
    for (int t = 0; t < 4; ++t) {
        alignas(8) __hip_bfloat16 ho[4];
#pragma unroll
        for (int r = 0; r < 4; ++r) ho[r] = __float2bfloat16(acc_o[t][r] * inv);
        *reinterpret_cast<ushort4*>(op + t * 16 + quad * 4) =
            *reinterpret_cast<ushort4*>(ho);
    }
}

// ---------------- launch ----------------
extern "C" void kernel_launch(void* const* d_in, const int* in_sizes, int n_in,
                              void* d_out, int out_size, void* d_ws, size_t ws_size,
                              hipStream_t stream) {
    const float* X  = (const float*)d_in[0];
    const float* Wq = (const float*)d_in[1];
    const float* Wk = (const float*)d_in[2];
    const float* Wv = (const float*)d_in[3];
    const float* Wo = (const float*)d_in[4];
    float* out = (float*)d_out;

    const int ROWS = 2 * S_LEN;               // 4096
    char* ws = (char*)d_ws;
    size_t off = 0;
    __hip_bfloat16* Xb     = (__hip_bfloat16*)(ws + off); off += (size_t)ROWS * DMODEL * 2;
    __hip_bfloat16* WqkvT  = (__hip_bfloat16*)(ws + off); off += (size_t)2048 * DMODEL * 2;
    __hip_bfloat16* WoT    = (__hip_bfloat16*)(ws + off); off += (size_t)DMODEL * DMODEL * 2;
    __hip_bfloat16* Qb     = (__hip_bfloat16*)(ws + off); off += (size_t)ROWS * (NH * HD) * 2;
    __hip_bfloat16* Kb     = (__hip_bfloat16*)(ws + off); off += (size_t)ROWS * (NKV * HD) * 2;
    __hip_bfloat16* VTg    = (__hip_bfloat16*)(ws + off); off += (size_t)ROWS * (NKV * HD) * 2;
    __hip_bfloat16* Ob     = (__hip_bfloat16*)(ws + off); off += (size_t)ROWS * (NH * HD) * 2;

    // 1. cast X; fused transpose of all weights
    cast_bf16_kernel<<<(ROWS * DMODEL) / (256 * 4), 256, 0, stream>>>(X, Xb, ROWS * DMODEL);
    transpose_cast4_kernel<<<dim3(32, 32, 4), dim3(32, 8), 0, stream>>>(
        Wq, Wk, Wv, Wo, WqkvT, WoT);

    // 2. fused QKV projection + in-register RoPE (Q,K) + V transpose
    gemm128_kernel<0><<<dim3(2048 / 128, ROWS / 64), 128, 0, stream>>>(
        Xb, WqkvT, Qb, Kb, VTg, 2048, DMODEL);

    // 3. MFMA flash attention (S^T, dbuf)
    attn_mfma_kernel<<<dim3(S_LEN / 64, NH, 2), 256, 0, stream>>>(Qb, Kb, VTg, Ob);

    // 4. output projection -> fp32
    gemm128_kernel<1><<<dim3(DMODEL / 128, ROWS / 64), 128, 0, stream>>>(
        Ob, WoT, out, nullptr, nullptr, DMODEL, DMODEL);
}

// Round 7
// 200.292 us; speedup vs baseline: 2.4135x; 2.4135x over previous
//
#include <hip/hip_runtime.h>
#include <hip/hip_bf16.h>

typedef __attribute__((ext_vector_type(8))) short short8;
typedef __attribute__((ext_vector_type(4))) float f32x4;

#define S_LEN 2048
#define NH 16
#define NKV 8
#define HD 64
#define WIN 512
#define DMODEL 1024
#define LOG2_10000 13.287712379549449f

// async 16B global -> LDS (wave-uniform LDS base + lane*16 semantics)
#define GLOAD16(g, l)                                                        \
    __builtin_amdgcn_global_load_lds(                                        \
        (const __attribute__((address_space(1))) unsigned int*)(g),          \
        (__attribute__((address_space(3))) unsigned int*)(l), 16, 0, 0)

// ---------------- cast X (fp32 -> bf16), vectorized ----------------
__global__ void cast_bf16_kernel(const float* __restrict__ X,
                                 __hip_bfloat16* __restrict__ Y, int n) {
    int i = (blockIdx.x * 256 + threadIdx.x) * 4;
    if (i + 3 < n) {
        float4 v = *reinterpret_cast<const float4*>(X + i);
        Y[i + 0] = __float2bfloat16(v.x);
        Y[i + 1] = __float2bfloat16(v.y);
        Y[i + 2] = __float2bfloat16(v.z);
        Y[i + 3] = __float2bfloat16(v.w);
    }
}

// ------- fused transpose+cast of all 4 weights (z selects matrix) -------
__global__ void transpose_cast4_kernel(const float* __restrict__ W0,
                                       const float* __restrict__ W1,
                                       const float* __restrict__ W2,
                                       const float* __restrict__ W3,
                                       __hip_bfloat16* __restrict__ WqkvT,
                                       __hip_bfloat16* __restrict__ WoT) {
    __shared__ float tile[32][33];
    const int K = DMODEL;
    const float* W;
    __hip_bfloat16* WT;
    int N;
    switch (blockIdx.z) {
        case 0: W = W0; WT = WqkvT;                          N = 1024; break;
        case 1: W = W1; WT = WqkvT + (size_t)1024 * K;       N = 512;  break;
        case 2: W = W2; WT = WqkvT + (size_t)1536 * K;       N = 512;  break;
        default: W = W3; WT = WoT;                           N = 1024; break;
    }
    if ((int)blockIdx.x * 32 >= N) return;
    int nx = blockIdx.x * 32 + threadIdx.x;
    int k0 = blockIdx.y * 32;
#pragma unroll
    for (int r = 0; r < 4; ++r) {
        int k = k0 + threadIdx.y + r * 8;
        tile[threadIdx.y + r * 8][threadIdx.x] = W[(size_t)k * N + nx];
    }
    __syncthreads();
#pragma unroll
    for (int r = 0; r < 4; ++r) {
        int nn = blockIdx.x * 32 + threadIdx.y + r * 8;
        int kk = k0 + threadIdx.x;
        WT[(size_t)nn * K + kk] = __float2bfloat16(tile[threadIdx.x][threadIdx.y + r * 8]);
    }
}

// ---------------- m97-style GEMM: 64(M)x128(N) tile, 128 thr = 2 waves ----------
// MODE 0: fused QKV epilogue with in-register RoPE on Q/K regions
//         (pairs (d, d+32) are acc[mi][ni] / acc[mi][ni+2]); V -> transposed.
//         RoPE uses __cosf/__sinf HW intrinsics (inline v_cos/v_sin) — libm
//         cosf/sinf are CALLS and forced the 64-VGPR acc array to spill
//         (round 6: VGPR=40, 1.68 GB scratch traffic, 330 us).
// MODE 1: fp32 C (row stride N).
template <int MODE>
__global__ __launch_bounds__(128) void gemm128_kernel(
    const __hip_bfloat16* __restrict__ A,
    const __hip_bfloat16* __restrict__ BT,
    void* __restrict__ o0, void* __restrict__ o1, void* __restrict__ o2,
    int N, int K) {
    __shared__ __hip_bfloat16 ldsA[64 * 32];    // 4 KB
    __shared__ __hip_bfloat16 ldsB[128 * 32];   // 8 KB
    const int tx = threadIdx.x;
    const int wave = tx >> 6;
    const int lane = tx & 63;
    const int l16 = lane & 15;
    const int quad = lane >> 4;
    const int col0 = blockIdx.x * 128;
    const int row0 = blockIdx.y * 64;
    const int wcol = wave * 64;

    f32x4 acc[4][4] = {};

    const int arow = tx >> 2;
    const int kc8 = (tx & 3) * 8;
    const __hip_bfloat16* gA = A + (size_t)(row0 + arow) * K + kc8;
    const __hip_bfloat16* gB = BT + (size_t)(col0 + arow) * K + kc8;
    char* lA = (char*)ldsA + tx * 16;
    char* lB = (char*)ldsB + tx * 16;

    for (int k0 = 0; k0 < K; k0 += 32) {
        GLOAD16(gA + k0, lA);
        GLOAD16(gA + (size_t)32 * K + k0, lA + 2048);
#pragma unroll
        for (int r = 0; r < 4; ++r)
            GLOAD16(gB + (size_t)r * 32 * K + k0, lB + r * 2048);
        __syncthreads();
        short8 af[4], bf[4];
#pragma unroll
        for (int i = 0; i < 4; ++i) {
            af[i] = *reinterpret_cast<const short8*>(ldsA + (i * 16 + l16) * 32 + quad * 8);
            bf[i] = *reinterpret_cast<const short8*>(ldsB + (wcol + i * 16 + l16) * 32 + quad * 8);
        }
#pragma unroll
        for (int mi = 0; mi < 4; ++mi)
#pragma unroll
            for (int ni = 0; ni < 4; ++ni)
                acc[mi][ni] = __builtin_amdgcn_mfma_f32_16x16x32_bf16(
                    af[mi], bf[ni], acc[mi][ni], 0, 0, 0);
        __syncthreads();
    }

    if (MODE == 0) {
        const bool isQ = (col0 < DMODEL);
        const bool isK = (col0 >= DMODEL) && (col0 < DMODEL + 512);
        if (isQ || isK) {
            // in-register RoPE: lane's d = ni*16 + l16 for ni<2, pair at ni+2
            float invf[2];
            invf[0] = exp2f(-(float)(l16)      * (LOG2_10000 / 32.0f));
            invf[1] = exp2f(-(float)(16 + l16) * (LOG2_10000 / 32.0f));
#pragma unroll
            for (int mi = 0; mi < 4; ++mi)
#pragma unroll
                for (int r = 0; r < 4; ++r) {
                    int srow = (row0 + mi * 16 + quad * 4 + r) & (S_LEN - 1);
#pragma unroll
                    for (int ni = 0; ni < 2; ++ni) {
                        float ang = (float)srow * invf[ni];
                        float c = __cosf(ang), s = __sinf(ang);
                        float x1 = acc[mi][ni][r], x2 = acc[mi][ni + 2][r];
                        acc[mi][ni][r]     = x1 * c - x2 * s;
                        acc[mi][ni + 2][r] = x2 * c + x1 * s;
                    }
                }
            __hip_bfloat16* Co = (__hip_bfloat16*)(isQ ? o0 : o1);
            int cbase = isQ ? col0 : col0 - DMODEL;
            int rowstride = isQ ? (NH * HD) : (NKV * HD);
#pragma unroll
            for (int mi = 0; mi < 4; ++mi)
#pragma unroll
                for (int ni = 0; ni < 4; ++ni) {
                    size_t col = cbase + wcol + ni * 16 + l16;
#pragma unroll
                    for (int r = 0; r < 4; ++r)
                        Co[(size_t)(row0 + mi * 16 + quad * 4 + r) * rowstride + col] =
                            __float2bfloat16(acc[mi][ni][r]);
                }
        } else {                                   // V region -> transposed VT
            __hip_bfloat16* VTo = (__hip_bfloat16*)o2;
            int bb = row0 >> 11;
#pragma unroll
            for (int mi = 0; mi < 4; ++mi) {
                int s = ((row0 + mi * 16 + quad * 4) & (S_LEN - 1));
#pragma unroll
                for (int ni = 0; ni < 4; ++ni) {
                    int colv = col0 - 1536 + wcol + ni * 16 + l16;   // 0..511
                    int vh = colv >> 6, d = colv & 63;
                    alignas(8) __hip_bfloat16 hv[4];
#pragma unroll
                    for (int r = 0; r < 4; ++r) hv[r] = __float2bfloat16(acc[mi][ni][r]);
                    *reinterpret_cast<ushort4*>(
                        VTo + ((size_t)(bb * NKV + vh) * HD + d) * S_LEN + s) =
                        *reinterpret_cast<ushort4*>(hv);
                }
            }
        }
    } else {                                       // fp32 C
        float* Co = (float*)o0;
#pragma unroll
        for (int mi = 0; mi < 4; ++mi)
#pragma unroll
            for (int ni = 0; ni < 4; ++ni) {
                size_t col = col0 + wcol + ni * 16 + l16;
#pragma unroll
                for (int r = 0; r < 4; ++r)
                    Co[(size_t)(row0 + mi * 16 + quad * 4 + r) * N + col] = acc[mi][ni][r];
            }
    }
}

// ---------------- MFMA flash attention (S^T, double-buffered staging) ----------
// grid (S/64, NH, B), 256 thr = 4 waves; lane owns 1 query (col) x 16 keys.
// Register-prefetch next K/V chunk during compute; ONE barrier per chunk.
// Softmax in exp2 domain (scale folds in log2e).
__global__ __launch_bounds__(256) void attn_mfma_kernel(
    const __hip_bfloat16* __restrict__ Q,
    const __hip_bfloat16* __restrict__ K,
    const __hip_bfloat16* __restrict__ VT,
    __hip_bfloat16* __restrict__ O) {
    __shared__ __hip_bfloat16 ldsK[2][64][80];
    __shared__ __hip_bfloat16 ldsVT[2][64][80];
    __shared__ __hip_bfloat16 ldsP[4][16][80];
    const int tx = threadIdx.x;
    const int wave = tx >> 6;
    const int lane = tx & 63;
    const int l16 = lane & 15;
    const int quad = lane >> 4;
    const int q0 = blockIdx.x * 64;
    const int h = blockIdx.y;
    const int b = blockIdx.z;
    const int kvh = h >> 1;
    const int qi = q0 + wave * 16 + l16;

    short8 aq0, aq1;
    {
        const __hip_bfloat16* qp =
            Q + (size_t)(b * S_LEN + qi) * (NH * HD) + h * HD + quad * 8;
        aq0 = *reinterpret_cast<const short8*>(qp);
        aq1 = *reinterpret_cast<const short8*>(qp + 32);
    }
    f32x4 acc_o[4] = {};
    float m = -1e30f, l = 0.f;
    const float SL2 = 0.125f * 1.4426950408889634f;   // scale * log2(e)

    const int s_a = tx >> 3;           // staging row   (0..31 per round)
    const int s_e = (tx & 7) * 8;      // staging elem offset
    uint4 kr[2], vr[2];
    auto load_chunk = [&](int j0) {
#pragma unroll
        for (int r = 0; r < 2; ++r) {
            int a = s_a + r * 32;
            kr[r] = *reinterpret_cast<const uint4*>(
                K + (size_t)(b * S_LEN + j0 + a) * (NKV * HD) + kvh * HD + s_e);
            vr[r] = *reinterpret_cast<const uint4*>(
                VT + ((size_t)(b * NKV + kvh) * HD + a) * S_LEN + j0 + s_e);
        }
    };
    const int kstart = (q0 >= WIN) ? (q0 - WIN) : 0;
    load_chunk(kstart);
    int buf = 0;

    for (int j0 = kstart; j0 <= q0; j0 += 64) {
#pragma unroll
        for (int r = 0; r < 2; ++r) {
            int a = s_a + r * 32;
            *reinterpret_cast<uint4*>(&ldsK[buf][a][s_e]) = kr[r];
            *reinterpret_cast<uint4*>(&ldsVT[buf][a][s_e]) = vr[r];
        }
        if (j0 + 64 <= q0) load_chunk(j0 + 64);
        __syncthreads();

        // S^T = K @ Q^T : rows = keys, cols = queries
        f32x4 sacc[4] = {};
#pragma unroll
        for (int t = 0; t < 4; ++t) {
            short8 bk0 = *reinterpret_cast<const short8*>(&ldsK[buf][t * 16 + l16][quad * 8]);
            short8 bk1 = *reinterpret_cast<const short8*>(&ldsK[buf][t * 16 + l16][32 + quad * 8]);
            sacc[t] = __builtin_amdgcn_mfma_f32_16x16x32_bf16(bk0, aq0, sacc[t], 0, 0, 0);
            sacc[t] = __builtin_amdgcn_mfma_f32_16x16x32_bf16(bk1, aq1, sacc[t], 0, 0, 0);
        }

        // scale into exp2 domain (+ mask only diagonal / trailing chunk)
        float sv[4][4];
        const bool need_mask = (j0 == q0) || (q0 >= WIN && j0 == kstart);
        if (need_mask) {
#pragma unroll
            for (int t = 0; t < 4; ++t)
#pragma unroll
                for (int r = 0; r < 4; ++r) {
                    int j = j0 + t * 16 + quad * 4 + r;
                    bool ok = (j <= qi) && (j + WIN >= qi);
                    sv[t][r] = ok ? sacc[t][r] * SL2 : -1e30f;
                }
        } else {
#pragma unroll
            for (int t = 0; t < 4; ++t)
#pragma unroll
                for (int r = 0; r < 4; ++r) sv[t][r] = sacc[t][r] * SL2;
        }

        // online softmax (exp2 domain): in-lane reduce + 2 shuffles
        float cm = -1e30f;
#pragma unroll
        for (int t = 0; t < 4; ++t)
#pragma unroll
            for (int r = 0; r < 4; ++r) cm = fmaxf(cm, sv[t][r]);
        cm = fmaxf(cm, __shfl_xor(cm, 16));
        cm = fmaxf(cm, __shfl_xor(cm, 32));
        float mn = fmaxf(m, cm);
        float alpha = exp2f(m - mn);
        m = mn;
        float sp = 0.f;
#pragma unroll
        for (int t = 0; t < 4; ++t)
#pragma unroll
            for (int r = 0; r < 4; ++r) { sv[t][r] = exp2f(sv[t][r] - mn); sp += sv[t][r]; }
        sp += __shfl_xor(sp, 16);
        sp += __shfl_xor(sp, 32);
        l = l * alpha + sp;
#pragma unroll
        for (int t = 0; t < 4; ++t)
#pragma unroll
            for (int r = 0; r < 4; ++r) acc_o[t][r] *= alpha;

        // P^T -> LDS (packed b64), then O^T += VT @ P^T (same-wave, in order)
#pragma unroll
        for (int t = 0; t < 4; ++t) {
            alignas(8) __hip_bfloat16 hp[4];
#pragma unroll
            for (int r = 0; r < 4; ++r) hp[r] = __float2bfloat16(sv[t][r]);
            *reinterpret_cast<ushort4*>(&ldsP[wave][l16][t * 16 + quad * 4]) =
                *reinterpret_cast<ushort4*>(hp);
        }
#pragma unroll
        for (int ks = 0; ks < 2; ++ks) {
            short8 pf = *reinterpret_cast<const short8*>(&ldsP[wave][l16][ks * 32 + quad * 8]);
#pragma unroll
            for (int t = 0; t < 4; ++t) {
                short8 vf = *reinterpret_cast<const short8*>(
                    &ldsVT[buf][t * 16 + l16][ks * 32 + quad * 8]);
                acc_o[t] = __builtin_amdgcn_mfma_f32_16x16x32_bf16(vf, pf, acc_o[t], 0, 0, 0);
            }
        }
        buf ^= 1;
    }

    float inv = 1.f / l;
    __hip_bfloat16* op = O + (size_t)(b * S_LEN + qi) * (NH * HD) + h * HD;
#pragma unroll
    for (int t = 0; t < 4; ++t) {
        alignas(8) __hip_bfloat16 ho[4];
#pragma unroll
        for (int r = 0; r < 4; ++r) ho[r] = __float2bfloat16(acc_o[t][r] * inv);
        *reinterpret_cast<ushort4*>(op + t * 16 + quad * 4) =
            *reinterpret_cast<ushort4*>(ho);
    }
}

// ---------------- launch ----------------
extern "C" void kernel_launch(void* const* d_in, const int* in_sizes, int n_in,
                              void* d_out, int out_size, void* d_ws, size_t ws_size,
                              hipStream_t stream) {
    const float* X  = (const float*)d_in[0];
    const float* Wq = (const float*)d_in[1];
    const float* Wk = (const float*)d_in[2];
    const float* Wv = (const float*)d_in[3];
    const float* Wo = (const float*)d_in[4];
    float* out = (float*)d_out;

    const int ROWS = 2 * S_LEN;               // 4096
    char* ws = (char*)d_ws;
    size_t off = 0;
    __hip_bfloat16* Xb     = (__hip_bfloat16*)(ws + off); off += (size_t)ROWS * DMODEL * 2;
    __hip_bfloat16* WqkvT  = (__hip_bfloat16*)(ws + off); off += (size_t)2048 * DMODEL * 2;
    __hip_bfloat16* WoT    = (__hip_bfloat16*)(ws + off); off += (size_t)DMODEL * DMODEL * 2;
    __hip_bfloat16* Qb     = (__hip_bfloat16*)(ws + off); off += (size_t)ROWS * (NH * HD) * 2;
    __hip_bfloat16* Kb     = (__hip_bfloat16*)(ws + off); off += (size_t)ROWS * (NKV * HD) * 2;
    __hip_bfloat16* VTg    = (__hip_bfloat16*)(ws + off); off += (size_t)ROWS * (NKV * HD) * 2;
    __hip_bfloat16* Ob     = (__hip_bfloat16*)(ws + off); off += (size_t)ROWS * (NH * HD) * 2;

    // 1. cast X; fused transpose of all weights
    cast_bf16_kernel<<<(ROWS * DMODEL) / (256 * 4), 256, 0, stream>>>(X, Xb, ROWS * DMODEL);
    transpose_cast4_kernel<<<dim3(32, 32, 4), dim3(32, 8), 0, stream>>>(
        Wq, Wk, Wv, Wo, WqkvT, WoT);

    // 2. fused QKV projection + in-register RoPE (Q,K) + V transpose
    gemm128_kernel<0><<<dim3(2048 / 128, ROWS / 64), 128, 0, stream>>>(
        Xb, WqkvT, Qb, Kb, VTg, 2048, DMODEL);

    // 3. MFMA flash attention (S^T, dbuf)
    attn_mfma_kernel<<<dim3(S_LEN / 64, NH, 2), 256, 0, stream>>>(Qb, Kb, VTg, Ob);

    // 4. output projection -> fp32
    gemm128_kernel<1><<<dim3(DMODEL / 128, ROWS / 64), 128, 0, stream>>>(
        Ob, WoT, out, nullptr, nullptr, DMODEL, DMODEL);
}

// Round 8
// 196.543 us; speedup vs baseline: 2.4596x; 1.0191x over previous
//
#include <hip/hip_runtime.h>
#include <hip/hip_bf16.h>

typedef __attribute__((ext_vector_type(8))) short short8;
typedef __attribute__((ext_vector_type(4))) float f32x4;

#define S_LEN 2048
#define NH 16
#define NKV 8
#define HD 64
#define WIN 512
#define DMODEL 1024
#define LOG2_10000 13.287712379549449f

// async 16B global -> LDS (wave-uniform LDS base + lane*16 semantics)
#define GLOAD16(g, l)                                                        \
    __builtin_amdgcn_global_load_lds(                                        \
        (const __attribute__((address_space(1))) unsigned int*)(g),          \
        (__attribute__((address_space(3))) unsigned int*)(l), 16, 0, 0)

// ---------------- cast X (fp32 -> bf16), vectorized ----------------
__global__ void cast_bf16_kernel(const float* __restrict__ X,
                                 __hip_bfloat16* __restrict__ Y, int n) {
    int i = (blockIdx.x * 256 + threadIdx.x) * 4;
    if (i + 3 < n) {
        float4 v = *reinterpret_cast<const float4*>(X + i);
        Y[i + 0] = __float2bfloat16(v.x);
        Y[i + 1] = __float2bfloat16(v.y);
        Y[i + 2] = __float2bfloat16(v.z);
        Y[i + 3] = __float2bfloat16(v.w);
    }
}

// ------- fused transpose+cast of all 4 weights (z selects matrix) -------
__global__ void transpose_cast4_kernel(const float* __restrict__ W0,
                                       const float* __restrict__ W1,
                                       const float* __restrict__ W2,
                                       const float* __restrict__ W3,
                                       __hip_bfloat16* __restrict__ WqkvT,
                                       __hip_bfloat16* __restrict__ WoT) {
    __shared__ float tile[32][33];
    const int K = DMODEL;
    const float* W;
    __hip_bfloat16* WT;
    int N;
    switch (blockIdx.z) {
        case 0: W = W0; WT = WqkvT;                          N = 1024; break;
        case 1: W = W1; WT = WqkvT + (size_t)1024 * K;       N = 512;  break;
        case 2: W = W2; WT = WqkvT + (size_t)1536 * K;       N = 512;  break;
        default: W = W3; WT = WoT;                           N = 1024; break;
    }
    if ((int)blockIdx.x * 32 >= N) return;
    int nx = blockIdx.x * 32 + threadIdx.x;
    int k0 = blockIdx.y * 32;
#pragma unroll
    for (int r = 0; r < 4; ++r) {
        int k = k0 + threadIdx.y + r * 8;
        tile[threadIdx.y + r * 8][threadIdx.x] = W[(size_t)k * N + nx];
    }
    __syncthreads();
#pragma unroll
    for (int r = 0; r < 4; ++r) {
        int nn = blockIdx.x * 32 + threadIdx.y + r * 8;
        int kk = k0 + threadIdx.x;
        WT[(size_t)nn * K + kk] = __float2bfloat16(tile[threadIdx.x][threadIdx.y + r * 8]);
    }
}

// ---------------- m97-geometry GEMM: 128x128 tile, 256 thr = 4 waves ----------
// Wave tile 64x64 (4x4 MFMA 16x16x32) -> 16 MFMA : 8 ds_read_b128 per iter
// (the 874 TF configuration). BK=32, GLOAD16 staging.
// MODE 0: fused QKV epilogue, in-register RoPE on Q/K (pairs (d,d+32) are
//         acc[mi][ni]/acc[mi][ni+2]; __cosf/__sinf ONLY — libm calls spill).
// MODE 1: fp32 C (row stride N).
template <int MODE>
__global__ __launch_bounds__(256) void gemm256_kernel(
    const __hip_bfloat16* __restrict__ A,
    const __hip_bfloat16* __restrict__ BT,
    void* __restrict__ o0, void* __restrict__ o1, void* __restrict__ o2,
    int N, int K) {
    __shared__ __hip_bfloat16 ldsA[128 * 32];   // 8 KB
    __shared__ __hip_bfloat16 ldsB[128 * 32];   // 8 KB
    const int tx = threadIdx.x;
    const int wave = tx >> 6;
    const int lane = tx & 63;
    const int l16 = lane & 15;
    const int quad = lane >> 4;
    const int col0 = blockIdx.x * 128;
    const int row0 = blockIdx.y * 128;
    const int wrow = (wave >> 1) * 64;
    const int wcol = (wave & 1) * 64;

    f32x4 acc[4][4] = {};

    const int arow = tx >> 2;            // 0..63
    const int kc8 = (tx & 3) * 8;
    const __hip_bfloat16* gA = A + (size_t)(row0 + arow) * K + kc8;
    const __hip_bfloat16* gB = BT + (size_t)(col0 + arow) * K + kc8;
    char* lA = (char*)ldsA + tx * 16;
    char* lB = (char*)ldsB + tx * 16;

    for (int k0 = 0; k0 < K; k0 += 32) {
        GLOAD16(gA + k0, lA);
        GLOAD16(gA + (size_t)64 * K + k0, lA + 4096);
        GLOAD16(gB + k0, lB);
        GLOAD16(gB + (size_t)64 * K + k0, lB + 4096);
        __syncthreads();
        short8 af[4], bf[4];
#pragma unroll
        for (int i = 0; i < 4; ++i) {
            af[i] = *reinterpret_cast<const short8*>(
                ldsA + (wrow + i * 16 + l16) * 32 + quad * 8);
            bf[i] = *reinterpret_cast<const short8*>(
                ldsB + (wcol + i * 16 + l16) * 32 + quad * 8);
        }
#pragma unroll
        for (int mi = 0; mi < 4; ++mi)
#pragma unroll
            for (int ni = 0; ni < 4; ++ni)
                acc[mi][ni] = __builtin_amdgcn_mfma_f32_16x16x32_bf16(
                    af[mi], bf[ni], acc[mi][ni], 0, 0, 0);
        __syncthreads();
    }

    const int rbase = row0 + wrow;
    if (MODE == 0) {
        const int cbaseg = col0 + wcol;             // 64-aligned global col
        const bool isQ = (cbaseg < DMODEL);
        const bool isK = (cbaseg >= DMODEL) && (cbaseg < DMODEL + 512);
        if (isQ || isK) {
            float invf[2];
            invf[0] = exp2f(-(float)(l16)      * (LOG2_10000 / 32.0f));
            invf[1] = exp2f(-(float)(16 + l16) * (LOG2_10000 / 32.0f));
#pragma unroll
            for (int mi = 0; mi < 4; ++mi)
#pragma unroll
                for (int r = 0; r < 4; ++r) {
                    int srow = (rbase + mi * 16 + quad * 4 + r) & (S_LEN - 1);
#pragma unroll
                    for (int ni = 0; ni < 2; ++ni) {
                        float ang = (float)srow * invf[ni];
                        float c = __cosf(ang), s = __sinf(ang);
                        float x1 = acc[mi][ni][r], x2 = acc[mi][ni + 2][r];
                        acc[mi][ni][r]     = x1 * c - x2 * s;
                        acc[mi][ni + 2][r] = x2 * c + x1 * s;
                    }
                }
            __hip_bfloat16* Co = (__hip_bfloat16*)(isQ ? o0 : o1);
            int cbase = isQ ? cbaseg : cbaseg - DMODEL;
            int rowstride = isQ ? (NH * HD) : (NKV * HD);
#pragma unroll
            for (int mi = 0; mi < 4; ++mi)
#pragma unroll
                for (int ni = 0; ni < 4; ++ni) {
                    size_t col = cbase + ni * 16 + l16;
#pragma unroll
                    for (int r = 0; r < 4; ++r)
                        Co[(size_t)(rbase + mi * 16 + quad * 4 + r) * rowstride + col] =
                            __float2bfloat16(acc[mi][ni][r]);
                }
        } else {                                   // V region -> transposed VT
            __hip_bfloat16* VTo = (__hip_bfloat16*)o2;
            int bb = row0 >> 11;
#pragma unroll
            for (int mi = 0; mi < 4; ++mi) {
                int s = ((rbase + mi * 16 + quad * 4) & (S_LEN - 1));
#pragma unroll
                for (int ni = 0; ni < 4; ++ni) {
                    int colv = cbaseg - 1536 + ni * 16 + l16;   // 0..511
                    int vh = colv >> 6, d = colv & 63;
                    alignas(8) __hip_bfloat16 hv[4];
#pragma unroll
                    for (int r = 0; r < 4; ++r) hv[r] = __float2bfloat16(acc[mi][ni][r]);
                    *reinterpret_cast<ushort4*>(
                        VTo + ((size_t)(bb * NKV + vh) * HD + d) * S_LEN + s) =
                        *reinterpret_cast<ushort4*>(hv);
                }
            }
        }
    } else {                                       // fp32 C
        float* Co = (float*)o0;
#pragma unroll
        for (int mi = 0; mi < 4; ++mi)
#pragma unroll
            for (int ni = 0; ni < 4; ++ni) {
                size_t col = col0 + wcol + ni * 16 + l16;
#pragma unroll
                for (int r = 0; r < 4; ++r)
                    Co[(size_t)(rbase + mi * 16 + quad * 4 + r) * N + col] = acc[mi][ni][r];
            }
    }
}

// ---------------- MFMA flash attention (S^T, dbuf, post-barrier prefetch) ------
// grid (S/64, NH, B), 256 thr = 4 waves; lane owns 1 query (col) x 16 keys.
// KEY FIX vs r7: prefetch is issued AFTER __syncthreads. The compiler drains
// vmcnt(0) before s_barrier, so loads issued just before the barrier stall it
// for their whole latency (r7: 58us). Issued after, they have the ~800-cycle
// compute section to land and only the next LDS-store waits on them.
__global__ __launch_bounds__(256) void attn_mfma_kernel(
    const __hip_bfloat16* __restrict__ Q,
    const __hip_bfloat16* __restrict__ K,
    const __hip_bfloat16* __restrict__ VT,
    __hip_bfloat16* __restrict__ O) {
    __shared__ __hip_bfloat16 ldsK[2][64][80];
    __shared__ __hip_bfloat16 ldsVT[2][64][80];
    __shared__ __hip_bfloat16 ldsP[4][16][80];
    const int tx = threadIdx.x;
    const int wave = tx >> 6;
    const int lane = tx & 63;
    const int l16 = lane & 15;
    const int quad = lane >> 4;
    const int q0 = blockIdx.x * 64;
    const int h = blockIdx.y;
    const int b = blockIdx.z;
    const int kvh = h >> 1;
    const int qi = q0 + wave * 16 + l16;

    short8 aq0, aq1;
    {
        const __hip_bfloat16* qp =
            Q + (size_t)(b * S_LEN + qi) * (NH * HD) + h * HD + quad * 8;
        aq0 = *reinterpret_cast<const short8*>(qp);
        aq1 = *reinterpret_cast<const short8*>(qp + 32);
    }
    f32x4 acc_o[4] = {};
    float m = -1e30f, l = 0.f;
    const float SL2 = 0.125f * 1.4426950408889634f;   // scale * log2(e)

    const int s_a = tx >> 3;
    const int s_e = (tx & 7) * 8;
    uint4 kr[2], vr[2];
    auto load_chunk = [&](int j0) {
#pragma unroll
        for (int r = 0; r < 2; ++r) {
            int a = s_a + r * 32;
            kr[r] = *reinterpret_cast<const uint4*>(
                K + (size_t)(b * S_LEN + j0 + a) * (NKV * HD) + kvh * HD + s_e);
            vr[r] = *reinterpret_cast<const uint4*>(
                VT + ((size_t)(b * NKV + kvh) * HD + a) * S_LEN + j0 + s_e);
        }
    };
    const int kstart = (q0 >= WIN) ? (q0 - WIN) : 0;
    load_chunk(kstart);
    int buf = 0;

    for (int j0 = kstart; j0 <= q0; j0 += 64) {
#pragma unroll
        for (int r = 0; r < 2; ++r) {
            int a = s_a + r * 32;
            *reinterpret_cast<uint4*>(&ldsK[buf][a][s_e]) = kr[r];
            *reinterpret_cast<uint4*>(&ldsVT[buf][a][s_e]) = vr[r];
        }
        __syncthreads();
        if (j0 + 64 <= q0) load_chunk(j0 + 64);   // post-barrier prefetch

        // S^T = K @ Q^T : rows = keys, cols = queries
        f32x4 sacc[4] = {};
#pragma unroll
        for (int t = 0; t < 4; ++t) {
            short8 bk0 = *reinterpret_cast<const short8*>(&ldsK[buf][t * 16 + l16][quad * 8]);
            short8 bk1 = *reinterpret_cast<const short8*>(&ldsK[buf][t * 16 + l16][32 + quad * 8]);
            sacc[t] = __builtin_amdgcn_mfma_f32_16x16x32_bf16(bk0, aq0, sacc[t], 0, 0, 0);
            sacc[t] = __builtin_amdgcn_mfma_f32_16x16x32_bf16(bk1, aq1, sacc[t], 0, 0, 0);
        }

        // scale into exp2 domain (+ mask only diagonal / trailing chunk)
        float sv[4][4];
        const bool need_mask = (j0 == q0) || (q0 >= WIN && j0 == kstart);
        if (need_mask) {
#pragma unroll
            for (int t = 0; t < 4; ++t)
#pragma unroll
                for (int r = 0; r < 4; ++r) {
                    int j = j0 + t * 16 + quad * 4 + r;
                    bool ok = (j <= qi) && (j + WIN >= qi);
                    sv[t][r] = ok ? sacc[t][r] * SL2 : -1e30f;
                }
        } else {
#pragma unroll
            for (int t = 0; t < 4; ++t)
#pragma unroll
                for (int r = 0; r < 4; ++r) sv[t][r] = sacc[t][r] * SL2;
        }

        // online softmax (exp2 domain): in-lane reduce + 2 shuffles
        float cm = -1e30f;
#pragma unroll
        for (int t = 0; t < 4; ++t)
#pragma unroll
            for (int r = 0; r < 4; ++r) cm = fmaxf(cm, sv[t][r]);
        cm = fmaxf(cm, __shfl_xor(cm, 16));
        cm = fmaxf(cm, __shfl_xor(cm, 32));
        float mn = fmaxf(m, cm);
        float alpha = exp2f(m - mn);
        m = mn;
        float sp = 0.f;
#pragma unroll
        for (int t = 0; t < 4; ++t)
#pragma unroll
            for (int r = 0; r < 4; ++r) { sv[t][r] = exp2f(sv[t][r] - mn); sp += sv[t][r]; }
        sp += __shfl_xor(sp, 16);
        sp += __shfl_xor(sp, 32);
        l = l * alpha + sp;
#pragma unroll
        for (int t = 0; t < 4; ++t)
#pragma unroll
            for (int r = 0; r < 4; ++r) acc_o[t][r] *= alpha;

        // P^T -> LDS (packed b64), then O^T += VT @ P^T (same-wave, in order)
#pragma unroll
        for (int t = 0; t < 4; ++t) {
            alignas(8) __hip_bfloat16 hp[4];
#pragma unroll
            for (int r = 0; r < 4; ++r) hp[r] = __float2bfloat16(sv[t][r]);
            *reinterpret_cast<ushort4*>(&ldsP[wave][l16][t * 16 + quad * 4]) =
                *reinterpret_cast<ushort4*>(hp);
        }
#pragma unroll
        for (int ks = 0; ks < 2; ++ks) {
            short8 pf = *reinterpret_cast<const short8*>(&ldsP[wave][l16][ks * 32 + quad * 8]);
#pragma unroll
            for (int t = 0; t < 4; ++t) {
                short8 vf = *reinterpret_cast<const short8*>(
                    &ldsVT[buf][t * 16 + l16][ks * 32 + quad * 8]);
                acc_o[t] = __builtin_amdgcn_mfma_f32_16x16x32_bf16(vf, pf, acc_o[t], 0, 0, 0);
            }
        }
        buf ^= 1;
    }

    float inv = 1.f / l;
    __hip_bfloat16* op = O + (size_t)(b * S_LEN + qi) * (NH * HD) + h * HD;
#pragma unroll
    for (int t = 0; t < 4; ++t) {
        alignas(8) __hip_bfloat16 ho[4];
#pragma unroll
        for (int r = 0; r < 4; ++r) ho[r] = __float2bfloat16(acc_o[t][r] * inv);
        *reinterpret_cast<ushort4*>(op + t * 16 + quad * 4) =
            *reinterpret_cast<ushort4*>(ho);
    }
}

// ---------------- launch ----------------
extern "C" void kernel_launch(void* const* d_in, const int* in_sizes, int n_in,
                              void* d_out, int out_size, void* d_ws, size_t ws_size,
                              hipStream_t stream) {
    const float* X  = (const float*)d_in[0];
    const float* Wq = (const float*)d_in[1];
    const float* Wk = (const float*)d_in[2];
    const float* Wv = (const float*)d_in[3];
    const float* Wo = (const float*)d_in[4];
    float* out = (float*)d_out;

    const int ROWS = 2 * S_LEN;               // 4096
    char* ws = (char*)d_ws;
    size_t off = 0;
    __hip_bfloat16* Xb     = (__hip_bfloat16*)(ws + off); off += (size_t)ROWS * DMODEL * 2;
    __hip_bfloat16* WqkvT  = (__hip_bfloat16*)(ws + off); off += (size_t)2048 * DMODEL * 2;
    __hip_bfloat16* WoT    = (__hip_bfloat16*)(ws + off); off += (size_t)DMODEL * DMODEL * 2;
    __hip_bfloat16* Qb     = (__hip_bfloat16*)(ws + off); off += (size_t)ROWS * (NH * HD) * 2;
    __hip_bfloat16* Kb     = (__hip_bfloat16*)(ws + off); off += (size_t)ROWS * (NKV * HD) * 2;
    __hip_bfloat16* VTg    = (__hip_bfloat16*)(ws + off); off += (size_t)ROWS * (NKV * HD) * 2;
    __hip_bfloat16* Ob     = (__hip_bfloat16*)(ws + off); off += (size_t)ROWS * (NH * HD) * 2;

    // 1. cast X; fused transpose of all weights
    cast_bf16_kernel<<<(ROWS * DMODEL) / (256 * 4), 256, 0, stream>>>(X, Xb, ROWS * DMODEL);
    transpose_cast4_kernel<<<dim3(32, 32, 4), dim3(32, 8), 0, stream>>>(
        Wq, Wk, Wv, Wo, WqkvT, WoT);

    // 2. fused QKV projection + in-register RoPE (Q,K) + V transpose
    gemm256_kernel<0><<<dim3(2048 / 128, ROWS / 128), 256, 0, stream>>>(
        Xb, WqkvT, Qb, Kb, VTg, 2048, DMODEL);

    // 3. MFMA flash attention (S^T, dbuf, post-barrier prefetch)
    attn_mfma_kernel<<<dim3(S_LEN / 64, NH, 2), 256, 0, stream>>>(Qb, Kb, VTg, Ob);

    // 4. output projection -> fp32
    gemm256_kernel<1><<<dim3(DMODEL / 128, ROWS / 128), 256, 0, stream>>>(
        Ob, WoT, out, nullptr, nullptr, DMODEL, DMODEL);
}

// Round 9
// 194.409 us; speedup vs baseline: 2.4866x; 1.0110x over previous
//
#include <hip/hip_runtime.h>
#include <hip/hip_bf16.h>

typedef __attribute__((ext_vector_type(8))) short short8;
typedef __attribute__((ext_vector_type(4))) float f32x4;

#define S_LEN 2048
#define NH 16
#define NKV 8
#define HD 64
#define WIN 512
#define DMODEL 1024
#define LOG2_10000 13.287712379549449f

// async 16B global -> LDS (wave-uniform LDS base + lane*16 semantics)
#define GLOAD16(g, l)                                                        \
    __builtin_amdgcn_global_load_lds(                                        \
        (const __attribute__((address_space(1))) unsigned int*)(g),          \
        (__attribute__((address_space(3))) unsigned int*)(l), 16, 0, 0)

// ---------------- cast X (fp32 -> bf16), vectorized ----------------
__global__ void cast_bf16_kernel(const float* __restrict__ X,
                                 __hip_bfloat16* __restrict__ Y, int n) {
    int i = (blockIdx.x * 256 + threadIdx.x) * 4;
    if (i + 3 < n) {
        float4 v = *reinterpret_cast<const float4*>(X + i);
        Y[i + 0] = __float2bfloat16(v.x);
        Y[i + 1] = __float2bfloat16(v.y);
        Y[i + 2] = __float2bfloat16(v.z);
        Y[i + 3] = __float2bfloat16(v.w);
    }
}

// ------- fused transpose+cast of all 4 weights (z selects matrix) -------
__global__ void transpose_cast4_kernel(const float* __restrict__ W0,
                                       const float* __restrict__ W1,
                                       const float* __restrict__ W2,
                                       const float* __restrict__ W3,
                                       __hip_bfloat16* __restrict__ WqkvT,
                                       __hip_bfloat16* __restrict__ WoT) {
    __shared__ float tile[32][33];
    const int K = DMODEL;
    const float* W;
    __hip_bfloat16* WT;
    int N;
    switch (blockIdx.z) {
        case 0: W = W0; WT = WqkvT;                          N = 1024; break;
        case 1: W = W1; WT = WqkvT + (size_t)1024 * K;       N = 512;  break;
        case 2: W = W2; WT = WqkvT + (size_t)1536 * K;       N = 512;  break;
        default: W = W3; WT = WoT;                           N = 1024; break;
    }
    if ((int)blockIdx.x * 32 >= N) return;
    int nx = blockIdx.x * 32 + threadIdx.x;
    int k0 = blockIdx.y * 32;
#pragma unroll
    for (int r = 0; r < 4; ++r) {
        int k = k0 + threadIdx.y + r * 8;
        tile[threadIdx.y + r * 8][threadIdx.x] = W[(size_t)k * N + nx];
    }
    __syncthreads();
#pragma unroll
    for (int r = 0; r < 4; ++r) {
        int nn = blockIdx.x * 32 + threadIdx.y + r * 8;
        int kk = k0 + threadIdx.x;
        WT[(size_t)nn * K + kk] = __float2bfloat16(tile[threadIdx.x][threadIdx.y + r * 8]);
    }
}

// ---------------- m97-geometry GEMM: 128x128 tile, 256 thr = 4 waves ----------
// Wave tile 64x64 (4x4 MFMA 16x16x32) -> 16 MFMA : 8 ds_read_b128 per iter.
// MODE 0: fused QKV epilogue, in-register RoPE on Q/K (__cosf/__sinf ONLY —
//         libm calls spill the acc array). MODE 1: fp32 C.
template <int MODE>
__global__ __launch_bounds__(256) void gemm256_kernel(
    const __hip_bfloat16* __restrict__ A,
    const __hip_bfloat16* __restrict__ BT,
    void* __restrict__ o0, void* __restrict__ o1, void* __restrict__ o2,
    int N, int K) {
    __shared__ __hip_bfloat16 ldsA[128 * 32];   // 8 KB
    __shared__ __hip_bfloat16 ldsB[128 * 32];   // 8 KB
    const int tx = threadIdx.x;
    const int wave = tx >> 6;
    const int lane = tx & 63;
    const int l16 = lane & 15;
    const int quad = lane >> 4;
    const int col0 = blockIdx.x * 128;
    const int row0 = blockIdx.y * 128;
    const int wrow = (wave >> 1) * 64;
    const int wcol = (wave & 1) * 64;

    f32x4 acc[4][4] = {};

    const int arow = tx >> 2;            // 0..63
    const int kc8 = (tx & 3) * 8;
    const __hip_bfloat16* gA = A + (size_t)(row0 + arow) * K + kc8;
    const __hip_bfloat16* gB = BT + (size_t)(col0 + arow) * K + kc8;
    char* lA = (char*)ldsA + tx * 16;
    char* lB = (char*)ldsB + tx * 16;

    for (int k0 = 0; k0 < K; k0 += 32) {
        GLOAD16(gA + k0, lA);
        GLOAD16(gA + (size_t)64 * K + k0, lA + 4096);
        GLOAD16(gB + k0, lB);
        GLOAD16(gB + (size_t)64 * K + k0, lB + 4096);
        __syncthreads();
        short8 af[4], bf[4];
#pragma unroll
        for (int i = 0; i < 4; ++i) {
            af[i] = *reinterpret_cast<const short8*>(
                ldsA + (wrow + i * 16 + l16) * 32 + quad * 8);
            bf[i] = *reinterpret_cast<const short8*>(
                ldsB + (wcol + i * 16 + l16) * 32 + quad * 8);
        }
#pragma unroll
        for (int mi = 0; mi < 4; ++mi)
#pragma unroll
            for (int ni = 0; ni < 4; ++ni)
                acc[mi][ni] = __builtin_amdgcn_mfma_f32_16x16x32_bf16(
                    af[mi], bf[ni], acc[mi][ni], 0, 0, 0);
        __syncthreads();
    }

    const int rbase = row0 + wrow;
    if (MODE == 0) {
        const int cbaseg = col0 + wcol;             // 64-aligned global col
        const bool isQ = (cbaseg < DMODEL);
        const bool isK = (cbaseg >= DMODEL) && (cbaseg < DMODEL + 512);
        if (isQ || isK) {
            float invf[2];
            invf[0] = exp2f(-(float)(l16)      * (LOG2_10000 / 32.0f));
            invf[1] = exp2f(-(float)(16 + l16) * (LOG2_10000 / 32.0f));
#pragma unroll
            for (int mi = 0; mi < 4; ++mi)
#pragma unroll
                for (int r = 0; r < 4; ++r) {
                    int srow = (rbase + mi * 16 + quad * 4 + r) & (S_LEN - 1);
#pragma unroll
                    for (int ni = 0; ni < 2; ++ni) {
                        float ang = (float)srow * invf[ni];
                        float c = __cosf(ang), s = __sinf(ang);
                        float x1 = acc[mi][ni][r], x2 = acc[mi][ni + 2][r];
                        acc[mi][ni][r]     = x1 * c - x2 * s;
                        acc[mi][ni + 2][r] = x2 * c + x1 * s;
                    }
                }
            __hip_bfloat16* Co = (__hip_bfloat16*)(isQ ? o0 : o1);
            int cbase = isQ ? cbaseg : cbaseg - DMODEL;
            int rowstride = isQ ? (NH * HD) : (NKV * HD);
#pragma unroll
            for (int mi = 0; mi < 4; ++mi)
#pragma unroll
                for (int ni = 0; ni < 4; ++ni) {
                    size_t col = cbase + ni * 16 + l16;
#pragma unroll
                    for (int r = 0; r < 4; ++r)
                        Co[(size_t)(rbase + mi * 16 + quad * 4 + r) * rowstride + col] =
                            __float2bfloat16(acc[mi][ni][r]);
                }
        } else {                                   // V region -> transposed VT
            __hip_bfloat16* VTo = (__hip_bfloat16*)o2;
            int bb = row0 >> 11;
#pragma unroll
            for (int mi = 0; mi < 4; ++mi) {
                int s = ((rbase + mi * 16 + quad * 4) & (S_LEN - 1));
#pragma unroll
                for (int ni = 0; ni < 4; ++ni) {
                    int colv = cbaseg - 1536 + ni * 16 + l16;   // 0..511
                    int vh = colv >> 6, d = colv & 63;
                    alignas(8) __hip_bfloat16 hv[4];
#pragma unroll
                    for (int r = 0; r < 4; ++r) hv[r] = __float2bfloat16(acc[mi][ni][r]);
                    *reinterpret_cast<ushort4*>(
                        VTo + ((size_t)(bb * NKV + vh) * HD + d) * S_LEN + s) =
                        *reinterpret_cast<ushort4*>(hv);
                }
            }
        }
    } else {                                       // fp32 C
        float* Co = (float*)o0;
#pragma unroll
        for (int mi = 0; mi < 4; ++mi)
#pragma unroll
            for (int ni = 0; ni < 4; ++ni) {
                size_t col = col0 + wcol + ni * 16 + l16;
#pragma unroll
                for (int r = 0; r < 4; ++r)
                    Co[(size_t)(rbase + mi * 16 + quad * 4 + r) * N + col] = acc[mi][ni][r];
            }
    }
}

// ---------------- MFMA flash attention (S^T, single-buf + reg prefetch) --------
// grid (S/64, NH, B), 256 thr = 4 waves; lane owns 1 query (col) x 16 keys.
// ROUND 9: r8 spilled (VGPR capped 68 by bare launch_bounds, 44 MB scratch
// writes) AND wasted 20 KB LDS on a dbuf made redundant by the register
// prefetch. Now: single K/V buffer (30.75 KB -> 4-5 blocks/CU), two barriers,
// __launch_bounds__(256,4) so the ~90 live VGPRs fit without spilling.
__global__ __launch_bounds__(256, 4) void attn_mfma_kernel(
    const __hip_bfloat16* __restrict__ Q,
    const __hip_bfloat16* __restrict__ K,
    const __hip_bfloat16* __restrict__ VT,
    __hip_bfloat16* __restrict__ O) {
    __shared__ __hip_bfloat16 ldsK[64][80];
    __shared__ __hip_bfloat16 ldsVT[64][80];
    __shared__ __hip_bfloat16 ldsP[4][16][80];
    const int tx = threadIdx.x;
    const int wave = tx >> 6;
    const int lane = tx & 63;
    const int l16 = lane & 15;
    const int quad = lane >> 4;
    const int q0 = blockIdx.x * 64;
    const int h = blockIdx.y;
    const int b = blockIdx.z;
    const int kvh = h >> 1;
    const int qi = q0 + wave * 16 + l16;

    short8 aq0, aq1;
    {
        const __hip_bfloat16* qp =
            Q + (size_t)(b * S_LEN + qi) * (NH * HD) + h * HD + quad * 8;
        aq0 = *reinterpret_cast<const short8*>(qp);
        aq1 = *reinterpret_cast<const short8*>(qp + 32);
    }
    f32x4 acc_o[4] = {};
    float m = -1e30f, l = 0.f;
    const float SL2 = 0.125f * 1.4426950408889634f;   // scale * log2(e)

    const int s_a = tx >> 3;
    const int s_e = (tx & 7) * 8;
    uint4 kr[2], vr[2];
    auto load_chunk = [&](int j0) {
#pragma unroll
        for (int r = 0; r < 2; ++r) {
            int a = s_a + r * 32;
            kr[r] = *reinterpret_cast<const uint4*>(
                K + (size_t)(b * S_LEN + j0 + a) * (NKV * HD) + kvh * HD + s_e);
            vr[r] = *reinterpret_cast<const uint4*>(
                VT + ((size_t)(b * NKV + kvh) * HD + a) * S_LEN + j0 + s_e);
        }
    };
    const int kstart = (q0 >= WIN) ? (q0 - WIN) : 0;
    load_chunk(kstart);

    for (int j0 = kstart; j0 <= q0; j0 += 64) {
#pragma unroll
        for (int r = 0; r < 2; ++r) {
            int a = s_a + r * 32;
            *reinterpret_cast<uint4*>(&ldsK[a][s_e]) = kr[r];
            *reinterpret_cast<uint4*>(&ldsVT[a][s_e]) = vr[r];
        }
        __syncthreads();                           // staging visible
        if (j0 + 64 <= q0) load_chunk(j0 + 64);    // prefetch overlaps compute

        // S^T = K @ Q^T : rows = keys, cols = queries
        f32x4 sacc[4] = {};
#pragma unroll
        for (int t = 0; t < 4; ++t) {
            short8 bk0 = *reinterpret_cast<const short8*>(&ldsK[t * 16 + l16][quad * 8]);
            short8 bk1 = *reinterpret_cast<const short8*>(&ldsK[t * 16 + l16][32 + quad * 8]);
            sacc[t] = __builtin_amdgcn_mfma_f32_16x16x32_bf16(bk0, aq0, sacc[t], 0, 0, 0);
            sacc[t] = __builtin_amdgcn_mfma_f32_16x16x32_bf16(bk1, aq1, sacc[t], 0, 0, 0);
        }

        // scale into exp2 domain (+ mask only diagonal / trailing chunk)
        float sv[4][4];
        const bool need_mask = (j0 == q0) || (q0 >= WIN && j0 == kstart);
        if (need_mask) {
#pragma unroll
            for (int t = 0; t < 4; ++t)
#pragma unroll
                for (int r = 0; r < 4; ++r) {
                    int j = j0 + t * 16 + quad * 4 + r;
                    bool ok = (j <= qi) && (j + WIN >= qi);
                    sv[t][r] = ok ? sacc[t][r] * SL2 : -1e30f;
                }
        } else {
#pragma unroll
            for (int t = 0; t < 4; ++t)
#pragma unroll
                for (int r = 0; r < 4; ++r) sv[t][r] = sacc[t][r] * SL2;
        }

        // online softmax (exp2 domain): in-lane reduce + 2 shuffles
        float cm = -1e30f;
#pragma unroll
        for (int t = 0; t < 4; ++t)
#pragma unroll
            for (int r = 0; r < 4; ++r) cm = fmaxf(cm, sv[t][r]);
        cm = fmaxf(cm, __shfl_xor(cm, 16));
        cm = fmaxf(cm, __shfl_xor(cm, 32));
        float mn = fmaxf(m, cm);
        float alpha = exp2f(m - mn);
        m = mn;
        float sp = 0.f;
#pragma unroll
        for (int t = 0; t < 4; ++t)
#pragma unroll
            for (int r = 0; r < 4; ++r) { sv[t][r] = exp2f(sv[t][r] - mn); sp += sv[t][r]; }
        sp += __shfl_xor(sp, 16);
        sp += __shfl_xor(sp, 32);
        l = l * alpha + sp;
#pragma unroll
        for (int t = 0; t < 4; ++t)
#pragma unroll
            for (int r = 0; r < 4; ++r) acc_o[t][r] *= alpha;

        // P^T -> LDS (packed b64; wave-private, no barrier needed)
#pragma unroll
        for (int t = 0; t < 4; ++t) {
            alignas(8) __hip_bfloat16 hp[4];
#pragma unroll
            for (int r = 0; r < 4; ++r) hp[r] = __float2bfloat16(sv[t][r]);
            *reinterpret_cast<ushort4*>(&ldsP[wave][l16][t * 16 + quad * 4]) =
                *reinterpret_cast<ushort4*>(hp);
        }
        // O^T += VT @ P^T
#pragma unroll
        for (int ks = 0; ks < 2; ++ks) {
            short8 pf = *reinterpret_cast<const short8*>(&ldsP[wave][l16][ks * 32 + quad * 8]);
#pragma unroll
            for (int t = 0; t < 4; ++t) {
                short8 vf = *reinterpret_cast<const short8*>(
                    &ldsVT[t * 16 + l16][ks * 32 + quad * 8]);
                acc_o[t] = __builtin_amdgcn_mfma_f32_16x16x32_bf16(vf, pf, acc_o[t], 0, 0, 0);
            }
        }
        __syncthreads();                           // all waves done with K/V LDS
    }

    float inv = 1.f / l;
    __hip_bfloat16* op = O + (size_t)(b * S_LEN + qi) * (NH * HD) + h * HD;
#pragma unroll
    for (int t = 0; t < 4; ++t) {
        alignas(8) __hip_bfloat16 ho[4];
#pragma unroll
        for (int r = 0; r < 4; ++r) ho[r] = __float2bfloat16(acc_o[t][r] * inv);
        *reinterpret_cast<ushort4*>(op + t * 16 + quad * 4) =
            *reinterpret_cast<ushort4*>(ho);
    }
}

// ---------------- launch ----------------
extern "C" void kernel_launch(void* const* d_in, const int* in_sizes, int n_in,
                              void* d_out, int out_size, void* d_ws, size_t ws_size,
                              hipStream_t stream) {
    const float* X  = (const float*)d_in[0];
    const float* Wq = (const float*)d_in[1];
    const float* Wk = (const float*)d_in[2];
    const float* Wv = (const float*)d_in[3];
    const float* Wo = (const float*)d_in[4];
    float* out = (float*)d_out;

    const int ROWS = 2 * S_LEN;               // 4096
    char* ws = (char*)d_ws;
    size_t off = 0;
    __hip_bfloat16* Xb     = (__hip_bfloat16*)(ws + off); off += (size_t)ROWS * DMODEL * 2;
    __hip_bfloat16* WqkvT  = (__hip_bfloat16*)(ws + off); off += (size_t)2048 * DMODEL * 2;
    __hip_bfloat16* WoT    = (__hip_bfloat16*)(ws + off); off += (size_t)DMODEL * DMODEL * 2;
    __hip_bfloat16* Qb     = (__hip_bfloat16*)(ws + off); off += (size_t)ROWS * (NH * HD) * 2;
    __hip_bfloat16* Kb     = (__hip_bfloat16*)(ws + off); off += (size_t)ROWS * (NKV * HD) * 2;
    __hip_bfloat16* VTg    = (__hip_bfloat16*)(ws + off); off += (size_t)ROWS * (NKV * HD) * 2;
    __hip_bfloat16* Ob     = (__hip_bfloat16*)(ws + off); off += (size_t)ROWS * (NH * HD) * 2;

    // 1. cast X; fused transpose of all weights
    cast_bf16_kernel<<<(ROWS * DMODEL) / (256 * 4), 256, 0, stream>>>(X, Xb, ROWS * DMODEL);
    transpose_cast4_kernel<<<dim3(32, 32, 4), dim3(32, 8), 0, stream>>>(
        Wq, Wk, Wv, Wo, WqkvT, WoT);

    // 2. fused QKV projection + in-register RoPE (Q,K) + V transpose
    gemm256_kernel<0><<<dim3(2048 / 128, ROWS / 128), 256, 0, stream>>>(
        Xb, WqkvT, Qb, Kb, VTg, 2048, DMODEL);

    // 3. MFMA flash attention (S^T, single-buf, reg prefetch, no spills)
    attn_mfma_kernel<<<dim3(S_LEN / 64, NH, 2), 256, 0, stream>>>(Qb, Kb, VTg, Ob);

    // 4. output projection -> fp32
    gemm256_kernel<1><<<dim3(DMODEL / 128, ROWS / 128), 256, 0, stream>>>(
        Ob, WoT, out, nullptr, nullptr, DMODEL, DMODEL);
}

// Round 10
// 174.709 us; speedup vs baseline: 2.7670x; 1.1128x over previous
//
#include <hip/hip_runtime.h>
#include <hip/hip_bf16.h>

typedef __attribute__((ext_vector_type(8))) short short8;
typedef __attribute__((ext_vector_type(4))) float f32x4;

#define S_LEN 2048
#define NH 16
#define NKV 8
#define HD 64
#define WIN 512
#define DMODEL 1024
#define LOG2_10000 13.287712379549449f

// async 16B global -> LDS (wave-uniform LDS base + lane*16 semantics)
#define GLOAD16(g, l)                                                        \
    __builtin_amdgcn_global_load_lds(                                        \
        (const __attribute__((address_space(1))) unsigned int*)(g),          \
        (__attribute__((address_space(3))) unsigned int*)(l), 16, 0, 0)

// ---------------- cast X (fp32 -> bf16), vectorized ----------------
__global__ void cast_bf16_kernel(const float* __restrict__ X,
                                 __hip_bfloat16* __restrict__ Y, int n) {
    int i = (blockIdx.x * 256 + threadIdx.x) * 4;
    if (i + 3 < n) {
        float4 v = *reinterpret_cast<const float4*>(X + i);
        Y[i + 0] = __float2bfloat16(v.x);
        Y[i + 1] = __float2bfloat16(v.y);
        Y[i + 2] = __float2bfloat16(v.z);
        Y[i + 3] = __float2bfloat16(v.w);
    }
}

// ------- fused transpose+cast of all 4 weights (z selects matrix) -------
__global__ void transpose_cast4_kernel(const float* __restrict__ W0,
                                       const float* __restrict__ W1,
                                       const float* __restrict__ W2,
                                       const float* __restrict__ W3,
                                       __hip_bfloat16* __restrict__ WqkvT,
                                       __hip_bfloat16* __restrict__ WoT) {
    __shared__ float tile[32][33];
    const int K = DMODEL;
    const float* W;
    __hip_bfloat16* WT;
    int N;
    switch (blockIdx.z) {
        case 0: W = W0; WT = WqkvT;                          N = 1024; break;
        case 1: W = W1; WT = WqkvT + (size_t)1024 * K;       N = 512;  break;
        case 2: W = W2; WT = WqkvT + (size_t)1536 * K;       N = 512;  break;
        default: W = W3; WT = WoT;                           N = 1024; break;
    }
    if ((int)blockIdx.x * 32 >= N) return;
    int nx = blockIdx.x * 32 + threadIdx.x;
    int k0 = blockIdx.y * 32;
#pragma unroll
    for (int r = 0; r < 4; ++r) {
        int k = k0 + threadIdx.y + r * 8;
        tile[threadIdx.y + r * 8][threadIdx.x] = W[(size_t)k * N + nx];
    }
    __syncthreads();
#pragma unroll
    for (int r = 0; r < 4; ++r) {
        int nn = blockIdx.x * 32 + threadIdx.y + r * 8;
        int kk = k0 + threadIdx.x;
        WT[(size_t)nn * K + kk] = __float2bfloat16(tile[threadIdx.x][threadIdx.y + r * 8]);
    }
}

// ---------------- m97-geometry GEMM: 128x128 tile, 256 thr = 4 waves ----------
// Wave tile 64x64 (4x4 MFMA 16x16x32) -> 16 MFMA : 8 ds_read_b128 per iter.
// MODE 0: fused QKV epilogue, in-register RoPE on Q/K (__cosf/__sinf ONLY —
//         libm calls spill the acc array). MODE 1: fp32 C.
template <int MODE>
__global__ __launch_bounds__(256) void gemm256_kernel(
    const __hip_bfloat16* __restrict__ A,
    const __hip_bfloat16* __restrict__ BT,
    void* __restrict__ o0, void* __restrict__ o1, void* __restrict__ o2,
    int N, int K) {
    __shared__ __hip_bfloat16 ldsA[128 * 32];   // 8 KB
    __shared__ __hip_bfloat16 ldsB[128 * 32];   // 8 KB
    const int tx = threadIdx.x;
    const int wave = tx >> 6;
    const int lane = tx & 63;
    const int l16 = lane & 15;
    const int quad = lane >> 4;
    const int col0 = blockIdx.x * 128;
    const int row0 = blockIdx.y * 128;
    const int wrow = (wave >> 1) * 64;
    const int wcol = (wave & 1) * 64;

    f32x4 acc[4][4] = {};

    const int arow = tx >> 2;            // 0..63
    const int kc8 = (tx & 3) * 8;
    const __hip_bfloat16* gA = A + (size_t)(row0 + arow) * K + kc8;
    const __hip_bfloat16* gB = BT + (size_t)(col0 + arow) * K + kc8;
    char* lA = (char*)ldsA + tx * 16;
    char* lB = (char*)ldsB + tx * 16;

    for (int k0 = 0; k0 < K; k0 += 32) {
        GLOAD16(gA + k0, lA);
        GLOAD16(gA + (size_t)64 * K + k0, lA + 4096);
        GLOAD16(gB + k0, lB);
        GLOAD16(gB + (size_t)64 * K + k0, lB + 4096);
        __syncthreads();
        short8 af[4], bf[4];
#pragma unroll
        for (int i = 0; i < 4; ++i) {
            af[i] = *reinterpret_cast<const short8*>(
                ldsA + (wrow + i * 16 + l16) * 32 + quad * 8);
            bf[i] = *reinterpret_cast<const short8*>(
                ldsB + (wcol + i * 16 + l16) * 32 + quad * 8);
        }
#pragma unroll
        for (int mi = 0; mi < 4; ++mi)
#pragma unroll
            for (int ni = 0; ni < 4; ++ni)
                acc[mi][ni] = __builtin_amdgcn_mfma_f32_16x16x32_bf16(
                    af[mi], bf[ni], acc[mi][ni], 0, 0, 0);
        __syncthreads();
    }

    const int rbase = row0 + wrow;
    if (MODE == 0) {
        const int cbaseg = col0 + wcol;             // 64-aligned global col
        const bool isQ = (cbaseg < DMODEL);
        const bool isK = (cbaseg >= DMODEL) && (cbaseg < DMODEL + 512);
        if (isQ || isK) {
            float invf[2];
            invf[0] = exp2f(-(float)(l16)      * (LOG2_10000 / 32.0f));
            invf[1] = exp2f(-(float)(16 + l16) * (LOG2_10000 / 32.0f));
#pragma unroll
            for (int mi = 0; mi < 4; ++mi)
#pragma unroll
                for (int r = 0; r < 4; ++r) {
                    int srow = (rbase + mi * 16 + quad * 4 + r) & (S_LEN - 1);
#pragma unroll
                    for (int ni = 0; ni < 2; ++ni) {
                        float ang = (float)srow * invf[ni];
                        float c = __cosf(ang), s = __sinf(ang);
                        float x1 = acc[mi][ni][r], x2 = acc[mi][ni + 2][r];
                        acc[mi][ni][r]     = x1 * c - x2 * s;
                        acc[mi][ni + 2][r] = x2 * c + x1 * s;
                    }
                }
            __hip_bfloat16* Co = (__hip_bfloat16*)(isQ ? o0 : o1);
            int cbase = isQ ? cbaseg : cbaseg - DMODEL;
            int rowstride = isQ ? (NH * HD) : (NKV * HD);
#pragma unroll
            for (int mi = 0; mi < 4; ++mi)
#pragma unroll
                for (int ni = 0; ni < 4; ++ni) {
                    size_t col = cbase + ni * 16 + l16;
#pragma unroll
                    for (int r = 0; r < 4; ++r)
                        Co[(size_t)(rbase + mi * 16 + quad * 4 + r) * rowstride + col] =
                            __float2bfloat16(acc[mi][ni][r]);
                }
        } else {                                   // V region -> transposed VT
            __hip_bfloat16* VTo = (__hip_bfloat16*)o2;
            int bb = row0 >> 11;
#pragma unroll
            for (int mi = 0; mi < 4; ++mi) {
                int s = ((rbase + mi * 16 + quad * 4) & (S_LEN - 1));
#pragma unroll
                for (int ni = 0; ni < 4; ++ni) {
                    int colv = cbaseg - 1536 + ni * 16 + l16;   // 0..511
                    int vh = colv >> 6, d = colv & 63;
                    alignas(8) __hip_bfloat16 hv[4];
#pragma unroll
                    for (int r = 0; r < 4; ++r) hv[r] = __float2bfloat16(acc[mi][ni][r]);
                    *reinterpret_cast<ushort4*>(
                        VTo + ((size_t)(bb * NKV + vh) * HD + d) * S_LEN + s) =
                        *reinterpret_cast<ushort4*>(hv);
                }
            }
        }
    } else {                                       // fp32 C
        float* Co = (float*)o0;
#pragma unroll
        for (int mi = 0; mi < 4; ++mi)
#pragma unroll
            for (int ni = 0; ni < 4; ++ni) {
                size_t col = col0 + wcol + ni * 16 + l16;
#pragma unroll
                for (int r = 0; r < 4; ++r)
                    Co[(size_t)(rbase + mi * 16 + quad * 4 + r) * N + col] = acc[mi][ni][r];
            }
    }
}

// ---------------- MFMA flash attention (S^T, async-DMA dbuf, XOR swizzle) ------
// grid (S/64, NH, B), 256 thr = 4 waves; lane owns 1 query (col) x 16 keys.
// ROUND 10: register prefetch (r7-r9) spilled 50-83 MB/dispatch (values live
// across barrier + MFMA section). Replaced with global_load_lds DMA dbuf:
// issue async loads for chunk j+1 into buf^1 right after the barrier; the
// compiler's vmcnt(0) drain sits at the NEXT barrier, one full compute
// section later. Zero staging VGPRs. GLOAD16 needs lane-linear LDS, so rows
// are unpadded 64x64; bank conflicts killed by XOR source swizzle:
// LDS[row][c] holds global chunk c^(row&7); readers use chunk q^(l16&7) —
// every b128 access lands at the 8-slot wave64 minimum (conflict-free).
__global__ __launch_bounds__(256) void attn_mfma_kernel(
    const __hip_bfloat16* __restrict__ Q,
    const __hip_bfloat16* __restrict__ K,
    const __hip_bfloat16* __restrict__ VT,
    __hip_bfloat16* __restrict__ O) {
    __shared__ __hip_bfloat16 ldsK[2][64][64];    // 16 KB
    __shared__ __hip_bfloat16 ldsVT[2][64][64];   // 16 KB
    __shared__ __hip_bfloat16 ldsP[4][16][80];    // 10.25 KB
    const int tx = threadIdx.x;
    const int wave = tx >> 6;
    const int lane = tx & 63;
    const int l16 = lane & 15;
    const int quad = lane >> 4;
    const int q0 = blockIdx.x * 64;
    const int h = blockIdx.y;
    const int b = blockIdx.z;
    const int kvh = h >> 1;
    const int qi = q0 + wave * 16 + l16;

    short8 aq0, aq1;
    {
        const __hip_bfloat16* qp =
            Q + (size_t)(b * S_LEN + qi) * (NH * HD) + h * HD + quad * 8;
        aq0 = *reinterpret_cast<const short8*>(qp);
        aq1 = *reinterpret_cast<const short8*>(qp + 32);
    }
    f32x4 acc_o[4] = {};
    float m = -1e30f, l = 0.f;
    const float SL2 = 0.125f * 1.4426950408889634f;   // scale * log2(e)

    // staging: thread tx covers (row = tx>>3 (+32), chunk-in-row = tx&7);
    // swizzled global source chunk = (tx&7) ^ (row&7)
    const int s_row = tx >> 3;
    const int s_c8 = (((tx & 7) ^ (s_row & 7))) * 8;   // element offset
    const int sw = (l16 & 7);                           // reader swizzle key
    auto stage = [&](int j0, int bf) {
        char* lk = (char*)(&ldsK[bf][0][0]) + tx * 16;
        char* lv = (char*)(&ldsVT[bf][0][0]) + tx * 16;
#pragma unroll
        for (int r = 0; r < 2; ++r) {
            int row = s_row + r * 32;
            GLOAD16(K + (size_t)(b * S_LEN + j0 + row) * (NKV * HD) + kvh * HD + s_c8,
                    lk + r * 4096);
            GLOAD16(VT + ((size_t)(b * NKV + kvh) * HD + row) * S_LEN + j0 + s_c8,
                    lv + r * 4096);
        }
    };

    const int kstart = (q0 >= WIN) ? (q0 - WIN) : 0;
    stage(kstart, 0);
    int buf = 0;

    for (int j0 = kstart; j0 <= q0; j0 += 64) {
        __syncthreads();                           // drains DMA into ldsK/VT[buf]
        if (j0 + 64 <= q0) stage(j0 + 64, buf ^ 1);   // async, lands by next barrier

        // S^T = K @ Q^T : rows = keys, cols = queries (swizzled chunk reads)
        f32x4 sacc[4] = {};
#pragma unroll
        for (int t = 0; t < 4; ++t) {
            const __hip_bfloat16* krow = &ldsK[buf][t * 16 + l16][0];
            short8 bk0 = *reinterpret_cast<const short8*>(krow + ((quad ^ sw) * 8));
            short8 bk1 = *reinterpret_cast<const short8*>(krow + (((4 + quad) ^ sw) * 8));
            sacc[t] = __builtin_amdgcn_mfma_f32_16x16x32_bf16(bk0, aq0, sacc[t], 0, 0, 0);
            sacc[t] = __builtin_amdgcn_mfma_f32_16x16x32_bf16(bk1, aq1, sacc[t], 0, 0, 0);
        }

        // scale into exp2 domain (+ mask only diagonal / trailing chunk)
        float sv[4][4];
        const bool need_mask = (j0 == q0) || (q0 >= WIN && j0 == kstart);
        if (need_mask) {
#pragma unroll
            for (int t = 0; t < 4; ++t)
#pragma unroll
                for (int r = 0; r < 4; ++r) {
                    int j = j0 + t * 16 + quad * 4 + r;
                    bool ok = (j <= qi) && (j + WIN >= qi);
                    sv[t][r] = ok ? sacc[t][r] * SL2 : -1e30f;
                }
        } else {
#pragma unroll
            for (int t = 0; t < 4; ++t)
#pragma unroll
                for (int r = 0; r < 4; ++r) sv[t][r] = sacc[t][r] * SL2;
        }

        // online softmax (exp2 domain): in-lane reduce + 2 shuffles
        float cm = -1e30f;
#pragma unroll
        for (int t = 0; t < 4; ++t)
#pragma unroll
            for (int r = 0; r < 4; ++r) cm = fmaxf(cm, sv[t][r]);
        cm = fmaxf(cm, __shfl_xor(cm, 16));
        cm = fmaxf(cm, __shfl_xor(cm, 32));
        float mn = fmaxf(m, cm);
        float alpha = exp2f(m - mn);
        m = mn;
        float sp = 0.f;
#pragma unroll
        for (int t = 0; t < 4; ++t)
#pragma unroll
            for (int r = 0; r < 4; ++r) { sv[t][r] = exp2f(sv[t][r] - mn); sp += sv[t][r]; }
        sp += __shfl_xor(sp, 16);
        sp += __shfl_xor(sp, 32);
        l = l * alpha + sp;
#pragma unroll
        for (int t = 0; t < 4; ++t)
#pragma unroll
            for (int r = 0; r < 4; ++r) acc_o[t][r] *= alpha;

        // P^T -> LDS (packed b64; wave-private, same-wave DS ordering)
#pragma unroll
        for (int t = 0; t < 4; ++t) {
            alignas(8) __hip_bfloat16 hp[4];
#pragma unroll
            for (int r = 0; r < 4; ++r) hp[r] = __float2bfloat16(sv[t][r]);
            *reinterpret_cast<ushort4*>(&ldsP[wave][l16][t * 16 + quad * 4]) =
                *reinterpret_cast<ushort4*>(hp);
        }
        // O^T += VT @ P^T (VT chunks swizzled)
#pragma unroll
        for (int ks = 0; ks < 2; ++ks) {
            short8 pf = *reinterpret_cast<const short8*>(&ldsP[wave][l16][ks * 32 + quad * 8]);
#pragma unroll
            for (int t = 0; t < 4; ++t) {
                const __hip_bfloat16* vrow = &ldsVT[buf][t * 16 + l16][0];
                short8 vf = *reinterpret_cast<const short8*>(
                    vrow + (((ks * 4 + quad) ^ sw) * 8));
                acc_o[t] = __builtin_amdgcn_mfma_f32_16x16x32_bf16(vf, pf, acc_o[t], 0, 0, 0);
            }
        }
        buf ^= 1;
    }

    float inv = 1.f / l;
    __hip_bfloat16* op = O + (size_t)(b * S_LEN + qi) * (NH * HD) + h * HD;
#pragma unroll
    for (int t = 0; t < 4; ++t) {
        alignas(8) __hip_bfloat16 ho[4];
#pragma unroll
        for (int r = 0; r < 4; ++r) ho[r] = __float2bfloat16(acc_o[t][r] * inv);
        *reinterpret_cast<ushort4*>(op + t * 16 + quad * 4) =
            *reinterpret_cast<ushort4*>(ho);
    }
}

// ---------------- launch ----------------
extern "C" void kernel_launch(void* const* d_in, const int* in_sizes, int n_in,
                              void* d_out, int out_size, void* d_ws, size_t ws_size,
                              hipStream_t stream) {
    const float* X  = (const float*)d_in[0];
    const float* Wq = (const float*)d_in[1];
    const float* Wk = (const float*)d_in[2];
    const float* Wv = (const float*)d_in[3];
    const float* Wo = (const float*)d_in[4];
    float* out = (float*)d_out;

    const int ROWS = 2 * S_LEN;               // 4096
    char* ws = (char*)d_ws;
    size_t off = 0;
    __hip_bfloat16* Xb     = (__hip_bfloat16*)(ws + off); off += (size_t)ROWS * DMODEL * 2;
    __hip_bfloat16* WqkvT  = (__hip_bfloat16*)(ws + off); off += (size_t)2048 * DMODEL * 2;
    __hip_bfloat16* WoT    = (__hip_bfloat16*)(ws + off); off += (size_t)DMODEL * DMODEL * 2;
    __hip_bfloat16* Qb     = (__hip_bfloat16*)(ws + off); off += (size_t)ROWS * (NH * HD) * 2;
    __hip_bfloat16* Kb     = (__hip_bfloat16*)(ws + off); off += (size_t)ROWS * (NKV * HD) * 2;
    __hip_bfloat16* VTg    = (__hip_bfloat16*)(ws + off); off += (size_t)ROWS * (NKV * HD) * 2;
    __hip_bfloat16* Ob     = (__hip_bfloat16*)(ws + off); off += (size_t)ROWS * (NH * HD) * 2;

    // 1. cast X; fused transpose of all weights
    cast_bf16_kernel<<<(ROWS * DMODEL) / (256 * 4), 256, 0, stream>>>(X, Xb, ROWS * DMODEL);
    transpose_cast4_kernel<<<dim3(32, 32, 4), dim3(32, 8), 0, stream>>>(
        Wq, Wk, Wv, Wo, WqkvT, WoT);

    // 2. fused QKV projection + in-register RoPE (Q,K) + V transpose
    gemm256_kernel<0><<<dim3(2048 / 128, ROWS / 128), 256, 0, stream>>>(
        Xb, WqkvT, Qb, Kb, VTg, 2048, DMODEL);

    // 3. MFMA flash attention (S^T, DMA dbuf, swizzled, no spills)
    attn_mfma_kernel<<<dim3(S_LEN / 64, NH, 2), 256, 0, stream>>>(Qb, Kb, VTg, Ob);

    // 4. output projection -> fp32
    gemm256_kernel<1><<<dim3(DMODEL / 128, ROWS / 128), 256, 0, stream>>>(
        Ob, WoT, out, nullptr, nullptr, DMODEL, DMODEL);
}